// Round 1
// baseline (245.511 us; speedup 1.0000x reference)
//
#include <hip/hip_runtime.h>
#include <math.h>

// Problem constants (B,C,L,K) = (32, 64, 4096, 512)
#define B_DIM 32
#define C_DIM 64
#define L_DIM 4096
#define K_CB  512
#define N_ROWS (B_DIM * L_DIM)            // 131072
#define Q_ELEMS (B_DIM * C_DIM * L_DIM)   // 8388608

// Output layout (float32, concatenated in return order):
// loss(1), quantized_st(B,C,L), perplexity(1), embed(K,C), indices(B,L), encodings(N,K)
#define OFF_LOSS  0
#define OFF_Q     1
#define OFF_PERP  (1 + Q_ELEMS)                  // 8388609
#define OFF_EMBED (OFF_PERP + 1)                 // 8388610
#define OFF_IDX   (OFF_EMBED + K_CB * C_DIM)     // 8421378
#define OFF_ENC   (OFF_IDX + N_ROWS)             // 8552450

#define TM 128   // rows per block in argmin kernel
#define KC 128   // codewords per LDS chunk

using f4 = __attribute__((ext_vector_type(4))) float;

// ---------------------------------------------------------------------------
// ws layout: [0:8) double loss accum; [16:16+2048) int hist[512];
//            [4096:4096+2048) float esq[512]
// ---------------------------------------------------------------------------

__global__ void vq_init(const float* __restrict__ embed,
                        double* __restrict__ loss_ws,
                        int* __restrict__ hist,
                        float* __restrict__ esq) {
  const int t = threadIdx.x;  // 512 threads, 1 block
  if (t == 0) *loss_ws = 0.0;
  hist[t] = 0;
  const float* row = embed + (size_t)t * C_DIM;
  float s = 0.f;
#pragma unroll
  for (int c = 0; c < C_DIM; ++c) s = fmaf(row[c], row[c], s);
  esq[t] = s;
}

// ---------------------------------------------------------------------------
// Distance GEMM + argmin. Block = 256 threads, owns TM=128 rows, loops K in
// chunks of KC=128 staged in LDS. Per-thread 8x8 register tile.
// ---------------------------------------------------------------------------
__global__ __launch_bounds__(256) void vq_argmin(
    const float* __restrict__ in, const float* __restrict__ embed,
    const float* __restrict__ esq_g, int* __restrict__ hist,
    float* __restrict__ out_idxf) {
  __shared__ float xT[C_DIM][TM];  // [c][row] transposed: conflict-free frag reads
  __shared__ float eT[KC][C_DIM];  // [k][c^swz] row-major with XOR bank swizzle

  const int tid = threadIdx.x;
  const int blk = blockIdx.x;            // 1024 blocks
  const int b   = blk >> 5;              // 32 l-chunks per batch element
  const int l0  = (blk & 31) * TM;
  const float* xbase = in + (size_t)b * C_DIM * L_DIM + l0;

  // Stage x tile: inputs[b][c][l0+r] -> xT[c][r], coalesced 512B rows
  {
    const int rr = (tid & 31) * 4;
    const int c0 = tid >> 5;  // 0..7
#pragma unroll
    for (int p = 0; p < 8; ++p) {
      const int c = c0 * 8 + p;
      const f4 v = *(const f4*)(xbase + (size_t)c * L_DIM + rr);
      *(f4*)&xT[c][rr] = v;
    }
  }
  __syncthreads();

  const int tx = tid & 15;   // codeword group
  const int ty = tid >> 4;   // row group (0..15), rows ty*8..ty*8+7

  // flat_sq per row (sequential over c, fp32 — see numerics note).
  // Use eT as scratch before first chunk staging.
  float* fsq_tmp = &eT[0][0];
  if (tid < TM) {
    float s = 0.f;
#pragma unroll
    for (int c = 0; c < C_DIM; ++c) { const float v = xT[c][tid]; s = fmaf(v, v, s); }
    fsq_tmp[tid] = s;
  }
  __syncthreads();
  float fs[8];
#pragma unroll
  for (int i = 0; i < 8; ++i) fs[i] = fsq_tmp[ty * 8 + i];

  const int swz = (tx & 7) << 2;  // bank-spread XOR for e fragment reads
  float rmin[8];
  int   ridx[8];
#pragma unroll
  for (int i = 0; i < 8; ++i) { rmin[i] = 3.402823466e38f; ridx[i] = 0; }

  for (int kc = 0; kc < K_CB / KC; ++kc) {
    const int k0 = kc * KC;
    __syncthreads();  // eT reuse boundary (fsq scratch / previous chunk reads)
    // Stage e chunk: embed[k0+kk][c] -> eT[kk][c ^ ((kk>>3&7)<<2)], coalesced reads
    {
      const int cg  = (tid & 15) * 4;
      const int kk0 = tid >> 4;  // 0..15
#pragma unroll
      for (int p = 0; p < 8; ++p) {
        const int kk = kk0 + p * 16;
        const f4 v = *(const f4*)(embed + (size_t)(k0 + kk) * C_DIM + cg);
        const int cs = cg ^ (((kk >> 3) & 7) << 2);
        *(f4*)&eT[kk][cs] = v;
      }
    }
    __syncthreads();

    float qe[8];
#pragma unroll
    for (int j = 0; j < 8; ++j) qe[j] = esq_g[k0 + tx * 8 + j];

    float acc[8][8];
#pragma unroll
    for (int i = 0; i < 8; ++i)
#pragma unroll
      for (int j = 0; j < 8; ++j) acc[i][j] = 0.f;

#pragma unroll 2
    for (int c = 0; c < C_DIM; c += 4) {
      f4 xa[4], xb[4], ev[8];
#pragma unroll
      for (int cc = 0; cc < 4; ++cc) {
        xa[cc] = *(const f4*)&xT[c + cc][ty * 8];
        xb[cc] = *(const f4*)&xT[c + cc][ty * 8 + 4];
      }
      const int cb = c ^ swz;
#pragma unroll
      for (int j = 0; j < 8; ++j)
        ev[j] = *(const f4*)&eT[tx * 8 + j][cb];
#pragma unroll
      for (int cc = 0; cc < 4; ++cc) {
#pragma unroll
        for (int j = 0; j < 8; ++j) {
          const float e = ev[j][cc];
#pragma unroll
          for (int i = 0; i < 4; ++i) acc[i][j]     = fmaf(xa[cc][i], e, acc[i][j]);
#pragma unroll
          for (int i = 0; i < 4; ++i) acc[i + 4][j] = fmaf(xb[cc][i], e, acc[i + 4][j]);
        }
      }
    }

    // d = (fsq + esq) - 2*dot  (single rounding via fma, matches np expression)
#pragma unroll
    for (int i = 0; i < 8; ++i) {
#pragma unroll
      for (int j = 0; j < 8; ++j) {
        const float d = fmaf(-2.0f, acc[i][j], fs[i] + qe[j]);
        const int k = k0 + tx * 8 + j;
        if (d < rmin[i]) { rmin[i] = d; ridx[i] = k; }  // strict <: first-min wins
      }
    }
  }

  // Reduce across the 16 tx lanes sharing each row group (lexicographic: d, then k)
#pragma unroll
  for (int off = 8; off; off >>= 1) {
#pragma unroll
    for (int i = 0; i < 8; ++i) {
      const float od = __shfl_xor(rmin[i], off, 16);
      const int   oi = __shfl_xor(ridx[i], off, 16);
      if (od < rmin[i] || (od == rmin[i] && oi < ridx[i])) { rmin[i] = od; ridx[i] = oi; }
    }
  }

  if (tx == 0) {
#pragma unroll
    for (int i = 0; i < 8; ++i) {
      const int n = blk * TM + ty * 8 + i;
      out_idxf[n] = (float)ridx[i];
      atomicAdd(&hist[ridx[i]], 1);
    }
  }
}

// ---------------------------------------------------------------------------
// quantized_st[b][c][l] = x + (e - x), and accumulate sum((e-x)^2) in double
// ---------------------------------------------------------------------------
__global__ void vq_quant(const float* __restrict__ in, const float* __restrict__ embed,
                         const float* __restrict__ idxf, float* __restrict__ outq,
                         double* __restrict__ loss_ws) {
  const unsigned stride = gridDim.x * blockDim.x;  // 524288
  double ls = 0.0;
  for (unsigned o = blockIdx.x * blockDim.x + threadIdx.x; o < Q_ELEMS; o += stride) {
    const int l = o & (L_DIM - 1);
    const int c = (o >> 12) & (C_DIM - 1);
    const int b = o >> 18;
    const int n = (b << 12) | l;
    const int k = (int)idxf[n];
    const float q = embed[k * C_DIM + c];
    const float x = in[o];
    const float d = q - x;              // fp32, as reference
    outq[o] = x + d;                    // straight-through: x + (q - x), as reference
    ls += (double)(d * d);              // square in fp32, accumulate in f64
  }
  __shared__ double red[256];
  red[threadIdx.x] = ls;
  __syncthreads();
  for (int s = 128; s; s >>= 1) {
    if ((int)threadIdx.x < s) red[threadIdx.x] += red[threadIdx.x + s];
    __syncthreads();
  }
  if (threadIdx.x == 0) atomicAdd(loss_ws, red[0]);
}

// ---------------------------------------------------------------------------
// Dense one-hot encodings (N x K), float2 stores (base is 8B-aligned only)
// ---------------------------------------------------------------------------
__global__ void vq_enc(const float* __restrict__ idxf, float2* __restrict__ enc) {
  const unsigned total = (unsigned)N_ROWS * (K_CB / 2);  // 33554432
  const unsigned stride = gridDim.x * blockDim.x;
  for (unsigned g = blockIdx.x * blockDim.x + threadIdx.x; g < total; g += stride) {
    const int n  = g >> 8;           // 256 float2 per row
    const int k2 = (g & 255) << 1;
    const int k  = (int)idxf[n];
    float2 v;
    v.x = (k2 == k)     ? 1.0f : 0.0f;
    v.y = (k2 + 1 == k) ? 1.0f : 0.0f;
    enc[g] = v;
  }
}

__global__ void vq_copy_embed(const float* __restrict__ embed, float* __restrict__ oe) {
  const int t = blockIdx.x * blockDim.x + threadIdx.x;  // 32768 threads
  oe[t] = embed[t];
}

__global__ void vq_final(const int* __restrict__ hist, const double* __restrict__ loss_ws,
                         float* __restrict__ out) {
  __shared__ float red[512];
  const int t = threadIdx.x;
  const float p = (float)hist[t] * (1.0f / (float)N_ROWS);
  red[t] = p * logf(p + 1e-10f);
  __syncthreads();
  for (int s = 256; s; s >>= 1) {
    if (t < s) red[t] += red[t + s];
    __syncthreads();
  }
  if (t == 0) {
    out[OFF_PERP] = expf(-red[0]);
    const float m = (float)(*loss_ws / (double)Q_ELEMS);  // mse (e_latent == q_latent)
    out[OFF_LOSS] = m + 0.25f * m;                        // q + 0.25*e, as reference
  }
}

extern "C" void kernel_launch(void* const* d_in, const int* in_sizes, int n_in,
                              void* d_out, int out_size, void* d_ws, size_t ws_size,
                              hipStream_t stream) {
  (void)in_sizes; (void)n_in; (void)out_size; (void)ws_size;
  const float* in    = (const float*)d_in[0];
  const float* embed = (const float*)d_in[1];
  float* out = (float*)d_out;

  double* loss_ws = (double*)d_ws;
  int*    hist    = (int*)((char*)d_ws + 16);
  float*  esq     = (float*)((char*)d_ws + 4096);

  vq_init<<<1, 512, 0, stream>>>(embed, loss_ws, hist, esq);
  vq_argmin<<<N_ROWS / TM, 256, 0, stream>>>(in, embed, esq, hist, out + OFF_IDX);
  vq_quant<<<2048, 256, 0, stream>>>(in, embed, out + OFF_IDX, out + OFF_Q, loss_ws);
  vq_enc<<<4096, 256, 0, stream>>>(out + OFF_IDX, (float2*)(out + OFF_ENC));
  vq_copy_embed<<<K_CB * C_DIM / 256, 256, 0, stream>>>(embed, out + OFF_EMBED);
  vq_final<<<1, 512, 0, stream>>>(hist, loss_ws, out);
}

// Round 3
// 170.532 us; speedup vs baseline: 1.4397x; 1.4397x over previous
//
#include <hip/hip_runtime.h>
#include <math.h>

// Problem constants (B,C,L,K) = (32, 64, 4096, 512)
#define B_DIM 32
#define C_DIM 64
#define L_DIM 4096
#define K_CB  512
#define N_ROWS (B_DIM * L_DIM)            // 131072
#define Q_ELEMS (B_DIM * C_DIM * L_DIM)   // 8388608

// Output layout (float32, concatenated in return order):
// loss(1), quantized_st(B,C,L), perplexity(1), embed(K,C), indices(B,L), encodings(N,K)
#define OFF_LOSS  0
#define OFF_Q     1
#define OFF_PERP  (1 + Q_ELEMS)
#define OFF_EMBED (OFF_PERP + 1)
#define OFF_IDX   (OFF_EMBED + K_CB * C_DIM)
#define OFF_ENC   (OFF_IDX + N_ROWS)

#define TM 128   // rows per block
#define KC 128   // codewords per LDS chunk

using f4 = __attribute__((ext_vector_type(4))) float;
using f2 = __attribute__((ext_vector_type(2))) float;

// ws layout: [0:8) double loss; [16:16+2048) int hist[512]; [4096:+2048) float esq[512]

__global__ void vq_init(const float* __restrict__ embed,
                        double* __restrict__ loss_ws,
                        int* __restrict__ hist,
                        float* __restrict__ esq,
                        float* __restrict__ out_embed) {
  const int t = threadIdx.x;  // 512 threads, 1 block
  if (t == 0) *loss_ws = 0.0;
  hist[t] = 0;
  const float* row = embed + (size_t)t * C_DIM;
  float s = 0.f;
#pragma unroll
  for (int c = 0; c < C_DIM; ++c) s = fmaf(row[c], row[c], s);
  esq[t] = s;
  // embed passthrough output (coalesced)
#pragma unroll
  for (int i = 0; i < K_CB * C_DIM / 512; ++i)
    out_embed[i * 512 + t] = embed[i * 512 + t];
}

// ---------------------------------------------------------------------------
// Fused: distance GEMM + argmin + indices + histogram + quantized_st + loss
// + one-hot encodings. Block = 256 threads owns TM=128 rows.
// ---------------------------------------------------------------------------
__global__ __launch_bounds__(256) void vq_fused(
    const float* __restrict__ in, const float* __restrict__ embed,
    const float* __restrict__ esq_g, int* __restrict__ hist,
    double* __restrict__ loss_ws, float* __restrict__ out) {
  __shared__ float xT[C_DIM][TM];   // [c][row] transposed input tile
  __shared__ float eT[KC][C_DIM];   // codebook chunk (later reused as eSel)
  __shared__ int   idx_s[TM];
  __shared__ double red[256];

  const int tid = threadIdx.x;
  const int blk = blockIdx.x;            // 1024 blocks
  const int b   = blk >> 5;
  const int l0  = (blk & 31) * TM;
  const float* xbase = in + (size_t)b * C_DIM * L_DIM + l0;

  // Stage x tile: inputs[b][c][l0+r] -> xT[c][r]
  {
    const int rr = (tid & 31) * 4;
    const int c0 = tid >> 5;
#pragma unroll
    for (int p = 0; p < 8; ++p) {
      const int c = c0 * 8 + p;
      const f4 v = *(const f4*)(xbase + (size_t)c * L_DIM + rr);
      *(f4*)&xT[c][rr] = v;
    }
  }
  __syncthreads();

  const int tx = tid & 15;   // codeword group
  const int ty = tid >> 4;   // row group

  // flat_sq per row (eT used as scratch)
  float* fsq_tmp = &eT[0][0];
  if (tid < TM) {
    float s = 0.f;
#pragma unroll
    for (int c = 0; c < C_DIM; ++c) { const float v = xT[c][tid]; s = fmaf(v, v, s); }
    fsq_tmp[tid] = s;
  }
  __syncthreads();
  float fs[8];
#pragma unroll
  for (int i = 0; i < 8; ++i) fs[i] = fsq_tmp[ty * 8 + i];

  const int swz = (tx & 7) << 2;
  float rmin[8];
  int   ridx[8];
#pragma unroll
  for (int i = 0; i < 8; ++i) { rmin[i] = 3.402823466e38f; ridx[i] = 0; }

  for (int kc = 0; kc < K_CB / KC; ++kc) {
    const int k0 = kc * KC;
    __syncthreads();
    {
      const int cg  = (tid & 15) * 4;
      const int kk0 = tid >> 4;
#pragma unroll
      for (int p = 0; p < 8; ++p) {
        const int kk = kk0 + p * 16;
        const f4 v = *(const f4*)(embed + (size_t)(k0 + kk) * C_DIM + cg);
        const int cs = cg ^ (((kk >> 3) & 7) << 2);
        *(f4*)&eT[kk][cs] = v;
      }
    }
    __syncthreads();

    float qe[8];
#pragma unroll
    for (int j = 0; j < 8; ++j) qe[j] = esq_g[k0 + tx * 8 + j];

    float acc[8][8];
#pragma unroll
    for (int i = 0; i < 8; ++i)
#pragma unroll
      for (int j = 0; j < 8; ++j) acc[i][j] = 0.f;

#pragma unroll 2
    for (int c = 0; c < C_DIM; c += 4) {
      f4 xa[4], xb[4], ev[8];
#pragma unroll
      for (int cc = 0; cc < 4; ++cc) {
        xa[cc] = *(const f4*)&xT[c + cc][ty * 8];
        xb[cc] = *(const f4*)&xT[c + cc][ty * 8 + 4];
      }
      const int cb = c ^ swz;
#pragma unroll
      for (int j = 0; j < 8; ++j)
        ev[j] = *(const f4*)&eT[tx * 8 + j][cb];
#pragma unroll
      for (int cc = 0; cc < 4; ++cc) {
#pragma unroll
        for (int j = 0; j < 8; ++j) {
          const float e = ev[j][cc];
#pragma unroll
          for (int i = 0; i < 4; ++i) acc[i][j]     = fmaf(xa[cc][i], e, acc[i][j]);
#pragma unroll
          for (int i = 0; i < 4; ++i) acc[i + 4][j] = fmaf(xb[cc][i], e, acc[i + 4][j]);
        }
      }
    }

#pragma unroll
    for (int i = 0; i < 8; ++i) {
#pragma unroll
      for (int j = 0; j < 8; ++j) {
        const float d = fmaf(-2.0f, acc[i][j], fs[i] + qe[j]);
        const int k = k0 + tx * 8 + j;
        if (d < rmin[i]) { rmin[i] = d; ridx[i] = k; }
      }
    }
  }

  // lexicographic cross-lane argmin reduce (first-occurrence semantics)
#pragma unroll
  for (int off = 8; off; off >>= 1) {
#pragma unroll
    for (int i = 0; i < 8; ++i) {
      const float od = __shfl_xor(rmin[i], off, 16);
      const int   oi = __shfl_xor(ridx[i], off, 16);
      if (od < rmin[i] || (od == rmin[i] && oi < ridx[i])) { rmin[i] = od; ridx[i] = oi; }
    }
  }

  if (tx == 0) {
#pragma unroll
    for (int i = 0; i < 8; ++i) idx_s[ty * 8 + i] = ridx[i];
  }
  __syncthreads();  // idx_s visible; all eT compute reads complete

  // --- indices + histogram ---
  if (tid < TM) {
    const int k = idx_s[tid];
    out[OFF_IDX + blk * TM + tid] = (float)k;
    atomicAdd(&hist[k], 1);
  }

  // --- stage selected codewords into eT (as eSel), swizzled for transpose ---
  // eSel[r][c ^ (r&31)]; writes: lanes share r, c varies -> all banks (free).
  {
    float* eSel = &eT[0][0];
    const int c = tid & 63;
    const int w = tid >> 6;  // wave id 0..3, one row per wave per iter
#pragma unroll 4
    for (int it = 0; it < 32; ++it) {
      const int r = it * 4 + w;
      const int k = idx_s[r];
      eSel[r * C_DIM + (c ^ (r & 31))] = embed[(size_t)k * C_DIM + c];
    }
  }
  __syncthreads();

  // --- quantized_st + loss: out[b][c][l0+r] = x + (e - x) ---
  double ls = 0.0;
  {
    const float* eSel = &eT[0][0];
    float* qbase = out + OFF_Q + (size_t)b * (C_DIM * L_DIM) + l0;
#pragma unroll 4
    for (int it = 0; it < 32; ++it) {
      const int f = it * 256 + tid;
      const int c = f >> 7;        // wave-uniform
      const int r = f & 127;       // lane-consecutive -> coalesced store
      const float x = xT[c][r];
      const float q = eSel[r * C_DIM + (c ^ (r & 31))];  // 2-way bank (free)
      const float d = q - x;
      __builtin_nontemporal_store(x + d, qbase + (size_t)c * L_DIM + r);
      ls += (double)(d * d);
    }
  }

  // --- one-hot encodings (f2 nontemporal; base is 8B aligned) ---
  {
    f2* enc = (f2*)(out + OFF_ENC) + (size_t)blk * TM * (K_CB / 2);
#pragma unroll 4
    for (int it = 0; it < 128; ++it) {
      const int g = it * 256 + tid;
      const int row = g >> 8;
      const int j2 = (g & 255) << 1;
      const int k = idx_s[row];
      f2 v;
      v.x = (j2 == k)     ? 1.0f : 0.0f;
      v.y = (j2 + 1 == k) ? 1.0f : 0.0f;
      __builtin_nontemporal_store(v, enc + g);
    }
  }

  // --- loss block-reduce (double) ---
  red[tid] = ls;
  __syncthreads();
  for (int s = 128; s; s >>= 1) {
    if (tid < s) red[tid] += red[tid + s];
    __syncthreads();
  }
  if (tid == 0) atomicAdd(loss_ws, red[0]);
}

__global__ void vq_final(const int* __restrict__ hist, const double* __restrict__ loss_ws,
                         float* __restrict__ out) {
  __shared__ float red[512];
  const int t = threadIdx.x;
  const float p = (float)hist[t] * (1.0f / (float)N_ROWS);
  red[t] = p * logf(p + 1e-10f);
  __syncthreads();
  for (int s = 256; s; s >>= 1) {
    if (t < s) red[t] += red[t + s];
    __syncthreads();
  }
  if (t == 0) {
    out[OFF_PERP] = expf(-red[0]);
    const float m = (float)(*loss_ws / (double)Q_ELEMS);
    out[OFF_LOSS] = m + 0.25f * m;
  }
}

extern "C" void kernel_launch(void* const* d_in, const int* in_sizes, int n_in,
                              void* d_out, int out_size, void* d_ws, size_t ws_size,
                              hipStream_t stream) {
  (void)in_sizes; (void)n_in; (void)out_size; (void)ws_size;
  const float* in    = (const float*)d_in[0];
  const float* embed = (const float*)d_in[1];
  float* out = (float*)d_out;

  double* loss_ws = (double*)d_ws;
  int*    hist    = (int*)((char*)d_ws + 16);
  float*  esq     = (float*)((char*)d_ws + 4096);

  vq_init<<<1, 512, 0, stream>>>(embed, loss_ws, hist, esq, out + OFF_EMBED);
  vq_fused<<<N_ROWS / TM, 256, 0, stream>>>(in, embed, esq, hist, loss_ws, out);
  vq_final<<<1, 512, 0, stream>>>(hist, loss_ws, out);
}

// Round 4
// 167.647 us; speedup vs baseline: 1.4645x; 1.0172x over previous
//
#include <hip/hip_runtime.h>
#include <math.h>

// Problem constants (B,C,L,K) = (32, 64, 4096, 512)
#define B_DIM 32
#define C_DIM 64
#define L_DIM 4096
#define K_CB  512
#define N_ROWS (B_DIM * L_DIM)            // 131072
#define Q_ELEMS (B_DIM * C_DIM * L_DIM)   // 8388608

// Output layout (float32, concatenated in return order):
// loss(1), quantized_st(B,C,L), perplexity(1), embed(K,C), indices(B,L), encodings(N,K)
#define OFF_LOSS  0
#define OFF_Q     1
#define OFF_PERP  (1 + Q_ELEMS)
#define OFF_EMBED (OFF_PERP + 1)
#define OFF_IDX   (OFF_EMBED + K_CB * C_DIM)
#define OFF_ENC   (OFF_IDX + N_ROWS)

#define TM 128   // rows per block
#define KC 64    // codewords per LDS chunk (8 chunks)

using f4 = __attribute__((ext_vector_type(4))) float;
using f2 = __attribute__((ext_vector_type(2))) float;

// ws layout: [0:8) double loss; [16:16+2048) int hist[512]; [4096:+2048) float esq[512]

__global__ void vq_init(const float* __restrict__ embed,
                        double* __restrict__ loss_ws,
                        int* __restrict__ hist,
                        float* __restrict__ esq,
                        float* __restrict__ out_embed) {
  const int t = threadIdx.x;  // 512 threads, 1 block
  if (t == 0) *loss_ws = 0.0;
  hist[t] = 0;
  const float* row = embed + (size_t)t * C_DIM;
  float s = 0.f;
#pragma unroll
  for (int c = 0; c < C_DIM; ++c) s = fmaf(row[c], row[c], s);
  esq[t] = s;
#pragma unroll
  for (int i = 0; i < K_CB * C_DIM / 512; ++i)
    out_embed[i * 512 + t] = embed[i * 512 + t];
}

// ---------------------------------------------------------------------------
// Fused: distance GEMM + argmin + indices + histogram + quantized_st + loss
// + one-hot encodings. 256 threads own TM=128 rows; K in 8 chunks of 64.
// LDS 50.5 KB -> 3 blocks/CU (12 waves/CU).
// ---------------------------------------------------------------------------
__global__ __launch_bounds__(256) void vq_fused(
    const float* __restrict__ in, const float* __restrict__ embed,
    const float* __restrict__ esq_g, int* __restrict__ hist,
    double* __restrict__ loss_ws, float* __restrict__ out) {
  __shared__ float xT[C_DIM][TM];   // 32 KB, [c][row] transposed input tile
  __shared__ float eT[KC][C_DIM];   // 16 KB, codebook chunk / eSel (2 passes)
  __shared__ int   idx_s[TM];
  __shared__ double red[256];

  const int tid = threadIdx.x;
  const int blk = blockIdx.x;            // 1024 blocks
  const int b   = blk >> 5;
  const int l0  = (blk & 31) * TM;
  const float* xbase = in + (size_t)b * C_DIM * L_DIM + l0;

  // Stage x tile: inputs[b][c][l0+r] -> xT[c][r]
  {
    const int rr = (tid & 31) * 4;
    const int c0 = tid >> 5;
#pragma unroll
    for (int p = 0; p < 8; ++p) {
      const int c = c0 * 8 + p;
      const f4 v = *(const f4*)(xbase + (size_t)c * L_DIM + rr);
      *(f4*)&xT[c][rr] = v;
    }
  }

  // Prefetch chunk 0 of embed into regs (global->reg, consumed after barrier)
  const int cg  = (tid & 15) * 4;   // c base for staging
  const int kk0 = tid >> 4;         // 0..15, rows kk0 + p*16
  f4 pf[4];
#pragma unroll
  for (int p = 0; p < 4; ++p)
    pf[p] = *(const f4*)(embed + (size_t)(kk0 + p * 16) * C_DIM + cg);

  __syncthreads();  // xT visible

  const int tx = tid & 15;   // codeword group (4 cw each)
  const int ty = tid >> 4;   // row group (8 rows each)

  // flat_sq per row (eT used as scratch before chunk 0 staged)
  float* fsq_tmp = &eT[0][0];
  if (tid < TM) {
    float s = 0.f;
#pragma unroll
    for (int c = 0; c < C_DIM; ++c) { const float v = xT[c][tid]; s = fmaf(v, v, s); }
    fsq_tmp[tid] = s;
  }
  __syncthreads();
  float fs[8];
#pragma unroll
  for (int i = 0; i < 8; ++i) fs[i] = fsq_tmp[ty * 8 + i];

  const int swz = tx << 2;  // read-side segment XOR (row>>2 == tx)
  float rmin[8];
  int   ridx[8];
#pragma unroll
  for (int i = 0; i < 8; ++i) { rmin[i] = 3.402823466e38f; ridx[i] = 0; }

  for (int kc = 0; kc < K_CB / KC; ++kc) {
    const int k0 = kc * KC;
    __syncthreads();  // previous eT consumers done (fsq reads / prev chunk)
    // Write prefetched chunk kc: eT[kk][c ^ ((kk>>2)<<2)]
#pragma unroll
    for (int p = 0; p < 4; ++p) {
      const int kk = kk0 + p * 16;
      const int cs = cg ^ (((kk >> 2) & 15) << 2);
      *(f4*)&eT[kk][cs] = pf[p];
    }
    // Issue prefetch of next chunk (completes during FMA loop)
    if (kc < K_CB / KC - 1) {
#pragma unroll
      for (int p = 0; p < 4; ++p)
        pf[p] = *(const f4*)(embed + (size_t)(k0 + KC + kk0 + p * 16) * C_DIM + cg);
    }
    float qe[4];
#pragma unroll
    for (int j = 0; j < 4; ++j) qe[j] = esq_g[k0 + tx * 4 + j];
    __syncthreads();  // eT ready

    float acc[8][4];
#pragma unroll
    for (int i = 0; i < 8; ++i)
#pragma unroll
      for (int j = 0; j < 4; ++j) acc[i][j] = 0.f;

#pragma unroll 2
    for (int c = 0; c < C_DIM; c += 4) {
      f4 xa[4], xb[4], ev[4];
#pragma unroll
      for (int cc = 0; cc < 4; ++cc) {
        xa[cc] = *(const f4*)&xT[c + cc][ty * 8];
        xb[cc] = *(const f4*)&xT[c + cc][ty * 8 + 4];
      }
      const int cb = c ^ swz;
#pragma unroll
      for (int j = 0; j < 4; ++j)
        ev[j] = *(const f4*)&eT[tx * 4 + j][cb];
#pragma unroll
      for (int cc = 0; cc < 4; ++cc) {
#pragma unroll
        for (int j = 0; j < 4; ++j) {
          const float e = ev[j][cc];
#pragma unroll
          for (int i = 0; i < 4; ++i) acc[i][j]     = fmaf(xa[cc][i], e, acc[i][j]);
#pragma unroll
          for (int i = 0; i < 4; ++i) acc[i + 4][j] = fmaf(xb[cc][i], e, acc[i + 4][j]);
        }
      }
    }

    // d = (fsq + esq) - 2*dot  (fma single-rounding; same eval order as before)
#pragma unroll
    for (int i = 0; i < 8; ++i) {
#pragma unroll
      for (int j = 0; j < 4; ++j) {
        const float d = fmaf(-2.0f, acc[i][j], fs[i] + qe[j]);
        const int k = k0 + tx * 4 + j;
        if (d < rmin[i]) { rmin[i] = d; ridx[i] = k; }  // strict <: first-min wins
      }
    }
  }

  // lexicographic cross-lane argmin reduce (first-occurrence semantics)
#pragma unroll
  for (int off = 8; off; off >>= 1) {
#pragma unroll
    for (int i = 0; i < 8; ++i) {
      const float od = __shfl_xor(rmin[i], off, 16);
      const int   oi = __shfl_xor(ridx[i], off, 16);
      if (od < rmin[i] || (od == rmin[i] && oi < ridx[i])) { rmin[i] = od; ridx[i] = oi; }
    }
  }

  if (tx == 0) {
#pragma unroll
    for (int i = 0; i < 8; ++i) idx_s[ty * 8 + i] = ridx[i];
  }
  __syncthreads();  // idx_s visible; all eT chunk reads complete

  // --- indices + histogram ---
  if (tid < TM) {
    const int k = idx_s[tid];
    out[OFF_IDX + blk * TM + tid] = (float)k;
    atomicAdd(&hist[k], 1);
  }

  // --- quantized_st + loss, 2 passes of 64 rows through eT (as eSel) ---
  double ls = 0.0;
  {
    float* eSel = &eT[0][0];
    float* qbase = out + OFF_Q + (size_t)b * (C_DIM * L_DIM) + l0;
    const int cc = tid & 63;
    const int w  = tid >> 6;  // wave id 0..3
#pragma unroll
    for (int pass = 0; pass < 2; ++pass) {
      const int r0 = pass * 64;
      __syncthreads();  // previous eT consumers done
      // stage selected codewords, swizzled: eSel[r][c ^ (r&31)]
#pragma unroll 4
      for (int it = 0; it < 16; ++it) {
        const int r = it * 4 + w;
        const int k = idx_s[r0 + r];
        eSel[r * C_DIM + (cc ^ (r & 31))] = embed[(size_t)k * C_DIM + cc];
      }
      __syncthreads();
      // quant: 64 rows x 64 c = 4096 elems, 16 iters of 256
#pragma unroll 4
      for (int it = 0; it < 16; ++it) {
        const int f = it * 256 + tid;
        const int c = f >> 6;        // wave-uniform
        const int r = f & 63;        // lane-consecutive -> coalesced store
        const float x = xT[c][r0 + r];
        const float q = eSel[r * C_DIM + (c ^ (r & 31))];  // 2-way bank (free)
        const float d = q - x;
        __builtin_nontemporal_store(x + d, qbase + (size_t)c * L_DIM + r0 + r);
        ls += (double)(d * d);
      }
    }
  }

  // --- one-hot encodings: row per iteration (idx broadcast), f2 stores ---
  {
    f2* enc = (f2*)(out + OFF_ENC) + (size_t)blk * TM * (K_CB / 2);
#pragma unroll 4
    for (int it = 0; it < TM; ++it) {
      const int k = idx_s[it];
      const int j2 = tid << 1;
      f2 v;
      v.x = (j2 == k)     ? 1.0f : 0.0f;
      v.y = (j2 + 1 == k) ? 1.0f : 0.0f;
      __builtin_nontemporal_store(v, enc + it * 256 + tid);
    }
  }

  // --- loss block-reduce (double) ---
  red[tid] = ls;
  __syncthreads();
  for (int s = 128; s; s >>= 1) {
    if (tid < s) red[tid] += red[tid + s];
    __syncthreads();
  }
  if (tid == 0) atomicAdd(loss_ws, red[0]);
}

__global__ void vq_final(const int* __restrict__ hist, const double* __restrict__ loss_ws,
                         float* __restrict__ out) {
  __shared__ float red[512];
  const int t = threadIdx.x;
  const float p = (float)hist[t] * (1.0f / (float)N_ROWS);
  red[t] = p * logf(p + 1e-10f);
  __syncthreads();
  for (int s = 256; s; s >>= 1) {
    if (t < s) red[t] += red[t + s];
    __syncthreads();
  }
  if (t == 0) {
    out[OFF_PERP] = expf(-red[0]);
    const float m = (float)(*loss_ws / (double)Q_ELEMS);
    out[OFF_LOSS] = m + 0.25f * m;
  }
}

extern "C" void kernel_launch(void* const* d_in, const int* in_sizes, int n_in,
                              void* d_out, int out_size, void* d_ws, size_t ws_size,
                              hipStream_t stream) {
  (void)in_sizes; (void)n_in; (void)out_size; (void)ws_size;
  const float* in    = (const float*)d_in[0];
  const float* embed = (const float*)d_in[1];
  float* out = (float*)d_out;

  double* loss_ws = (double*)d_ws;
  int*    hist    = (int*)((char*)d_ws + 16);
  float*  esq     = (float*)((char*)d_ws + 4096);

  vq_init<<<1, 512, 0, stream>>>(embed, loss_ws, hist, esq, out + OFF_EMBED);
  vq_fused<<<N_ROWS / TM, 256, 0, stream>>>(in, embed, esq, hist, loss_ws, out);
  vq_final<<<1, 512, 0, stream>>>(hist, loss_ws, out);
}